// Round 2
// baseline (106.723 us; speedup 1.0000x reference)
//
#include <hip/hip_runtime.h>

// ---------------------------------------------------------------------------
// SpaceTimeStepLookTable: fused gather + relu + bf16 MFMA GEMM + projection
//
// Feature layout (original k): f0[0,64) f1[64,576) f2[576,4672) f3[4672,37440)
//                              time[37440,37632) nb[37632,37848)
// Packed layout (kp):  dense[0,1024) = [f0|f1|time|nb|zeros40]
//                      f2   [1024,5120)
//                      f3   [5120,37888)
// ---------------------------------------------------------------------------

typedef short s16x8 __attribute__((ext_vector_type(8)));
typedef float f32x4 __attribute__((ext_vector_type(4)));

#define N_PTS 2048
#define KP_TOTAL 37888
#define K_ORIG 37848
#define BM 64
#define BK 64
#define KSPLIT 32
#define NCHUNK 592                // 37888 / 64
#define LDS_PAD 72                // bf16 elems per LDS row (144B: balanced banks)
#define PACK_BLOCKS 18944         // 148 * 128

__device__ __forceinline__ unsigned short f2bf(float x) {
    unsigned u = __builtin_bit_cast(unsigned, x);
    u = (u + 0x7FFFu + ((u >> 16) & 1u)) >> 16;   // RNE
    return (unsigned short)u;
}

// ---------------------------------------------------------------------------
// Kernel 1 (fused setup): blocks [0,18944) pack W_mlp -> bf16 permuted;
// blocks [18944, 20992) do per-point prep of the dense segment + bases.
// ---------------------------------------------------------------------------
__global__ void setup_kernel(const float* __restrict__ Wm, unsigned short* __restrict__ Wp,
                             const float* __restrict__ pos, const float* __restrict__ t,
                             const float* __restrict__ table0, const float* __restrict__ table1,
                             const float* __restrict__ ts1, const float* __restrict__ ts2,
                             float* __restrict__ dense, int* __restrict__ bases) {
    const int b = blockIdx.x;
    const int tid = threadIdx.x;
    if (b < PACK_BLOCKS) {
        // ---- pack_w ----
        const int c  = b / 148;                 // [0,128)
        const int kp = (b % 148) * 256 + tid;   // [0,37888)
        int k; bool valid = true;
        if (kp < 576)        k = kp;                       // f0+f1
        else if (kp < 768)   k = 37440 + (kp - 576);       // time
        else if (kp < 984)   k = 37632 + (kp - 768);       // nb
        else if (kp < 1024)  { k = 0; valid = false; }     // zero pad
        else if (kp < 5120)  k = 576 + (kp - 1024);        // f2
        else                 k = 4672 + (kp - 5120);       // f3
        const float w = valid ? Wm[(size_t)c * K_ORIG + k] : 0.f;
        Wp[(size_t)c * KP_TOTAL + kp] = f2bf(w);
        return;
    }
    // ---- prep ----
    const int n = b - PACK_BLOCKS;
    const float px = pos[3 * n], py = pos[3 * n + 1], pz = pos[3 * n + 2];
    const float tv = t[n];
    const int i0 = (int)(px * 127.f), j0 = (int)(py * 127.f), k0 = (int)(pz * 127.f);
    const int i1 = (int)(px * 63.f),  j1 = (int)(py * 63.f),  k1 = (int)(pz * 63.f);
    const int i2 = (int)(px * 31.f),  j2 = (int)(py * 31.f),  k2 = (int)(pz * 31.f);
    const int i3 = (int)(px * 15.f),  j3 = (int)(py * 15.f),  k3 = (int)(pz * 15.f);
    const int ti = (int)(tv * 127.f);

    float* drow = dense + (size_t)n * 1024;

    if (tid < 64)
        drow[tid] = table0[(size_t)(((i0 * 128 + j0) * 128 + k0)) * 64 + tid];
    #pragma unroll
    for (int e = tid; e < 512; e += 256)
        drow[64 + e] = table1[(size_t)(((i1 * 64 + j1) * 64 + k1)) * 512 + e];
    if (tid < 192) {
        const int d = tid >> 6, e = tid & 63;
        const int tw = (ti + d - 1 + 64) & 63;
        drow[576 + tid] = ts1[((size_t)(((i3 * 16 + j3) * 16 + k3)) * 64 + tw) * 64 + e];
    }
    if (tid < 216) {
        const int o = tid >> 2, cc = tid & 3;
        const int dt_ = (o & 1) ? 1 : -1;
        const int rest = o >> 1;
        const int dz_ = rest % 3 - 1;
        const int dy_ = (rest / 3) % 3 - 1;
        const int dx_ = rest / 9 - 1;
        const int x = (i3 + dx_ + 128) & 127;
        const int y = (j3 + dy_ + 128) & 127;
        const int z = (k3 + dz_ + 128) & 127;
        const int w = (ti + dt_ + 128) & 127;
        drow[768 + tid] = ts2[(((((size_t)x * 128 + y) * 128 + z) * 128 + w) * 4) + cc];
    } else if (tid >= 216 && tid < 256) {
        drow[768 + tid] = 0.f;    // kp [984,1024) zero pad
    }
    if (tid == 0) {
        bases[2 * n]     = ((i2 * 32 + j2) * 32 + k2) * 4096;   // f2 row base (elements)
        bases[2 * n + 1] = ((i3 * 16 + j3) * 16 + k3) * 32768;  // f3 row base (elements)
    }
}

// ---------------------------------------------------------------------------
// Kernel 2: fused gather->relu->bf16 GEMM. C = relu(A) * W^T, split-K.
// grid (KSPLIT=32, 32 m-tiles) x 256 threads. 4 blocks/CU.
// Software-prefetched: chunk c+1's global loads issue before chunk c's MFMAs.
// ---------------------------------------------------------------------------
__global__ __launch_bounds__(256, 4) void gemm_kernel(
    const float* __restrict__ dense, const float* __restrict__ table2,
    const float* __restrict__ table3, const int* __restrict__ bases,
    const unsigned short* __restrict__ Wp, float* __restrict__ part) {

    __shared__ unsigned short Alds[BM][LDS_PAD];
    __shared__ unsigned short Wlds[128][LDS_PAD];

    const int ks = blockIdx.x;
    const int mt = blockIdx.y;
    const int row0 = mt * BM;
    const int tid = threadIdx.x;
    const int lane = tid & 63;
    const int wave = tid >> 6;
    const int wm = wave >> 1;   // 0..1 (32-row half)
    const int wn = wave & 1;    // 0..1 (64-col half)

    // A staging: each thread loads 16 consecutive fp32 of one row
    const int arow = tid >> 2;
    const int acol = (tid & 3) * 16;
    const int an = row0 + arow;
    const int f2b = bases[2 * an];
    const int f3b = bases[2 * an + 1];
    const float* drow = dense + (size_t)an * 1024;

    // W staging: each thread copies 32 bf16 of one row
    const int wrow = tid >> 1;
    const int wcol = (tid & 1) * 32;
    const unsigned short* wrowp = Wp + (size_t)wrow * KP_TOTAL;

    f32x4 acc[2][4];
    #pragma unroll
    for (int i = 0; i < 2; ++i)
        #pragma unroll
        for (int j = 0; j < 4; ++j)
            acc[i][j] = (f32x4){0.f, 0.f, 0.f, 0.f};

    const int cbeg = (ks * NCHUNK) >> 5;
    const int cend = ((ks + 1) * NCHUNK) >> 5;

    float4 av0, av1, av2, av3;
    s16x8 wv0, wv1, wv2, wv3;

    auto load_regs = [&](int c) {
        const int kp0 = c * BK;
        const float* asrc;
        if (kp0 < 1024)      asrc = drow + kp0 + acol;
        else if (kp0 < 5120) asrc = table2 + (size_t)f2b + (kp0 - 1024) + acol;
        else                 asrc = table3 + (size_t)f3b + (kp0 - 5120) + acol;
        av0 = ((const float4*)asrc)[0];
        av1 = ((const float4*)asrc)[1];
        av2 = ((const float4*)asrc)[2];
        av3 = ((const float4*)asrc)[3];
        const s16x8* wsrc = (const s16x8*)(wrowp + kp0 + wcol);
        wv0 = wsrc[0]; wv1 = wsrc[1]; wv2 = wsrc[2]; wv3 = wsrc[3];
    };

    load_regs(cbeg);

    for (int c = cbeg; c < cend; ++c) {
        __syncthreads();   // previous round's LDS reads complete

        float va[16];
        *(float4*)&va[0] = av0; *(float4*)&va[4] = av1;
        *(float4*)&va[8] = av2; *(float4*)&va[12] = av3;
        s16x8 o0, o1;
        #pragma unroll
        for (int e = 0; e < 8; ++e) {
            o0[e] = (short)f2bf(fmaxf(va[e], 0.f));
            o1[e] = (short)f2bf(fmaxf(va[e + 8], 0.f));
        }
        *(s16x8*)&Alds[arow][acol]      = o0;
        *(s16x8*)&Alds[arow][acol + 8]  = o1;
        *(s16x8*)&Wlds[wrow][wcol]      = wv0;
        *(s16x8*)&Wlds[wrow][wcol + 8]  = wv1;
        *(s16x8*)&Wlds[wrow][wcol + 16] = wv2;
        *(s16x8*)&Wlds[wrow][wcol + 24] = wv3;

        __syncthreads();

        if (c + 1 < cend) load_regs(c + 1);   // prefetch overlaps MFMAs below

        #pragma unroll
        for (int kk = 0; kk < 2; ++kk) {
            const int ko = kk * 32 + (lane >> 4) * 8;
            const int r = lane & 15;
            const s16x8 a0 = *(const s16x8*)&Alds[wm * 32 + r][ko];
            const s16x8 a1 = *(const s16x8*)&Alds[wm * 32 + 16 + r][ko];
            const s16x8 b0 = *(const s16x8*)&Wlds[wn * 64 + r][ko];
            const s16x8 b1 = *(const s16x8*)&Wlds[wn * 64 + 16 + r][ko];
            const s16x8 b2 = *(const s16x8*)&Wlds[wn * 64 + 32 + r][ko];
            const s16x8 b3 = *(const s16x8*)&Wlds[wn * 64 + 48 + r][ko];
            acc[0][0] = __builtin_amdgcn_mfma_f32_16x16x32_bf16(a0, b0, acc[0][0], 0, 0, 0);
            acc[0][1] = __builtin_amdgcn_mfma_f32_16x16x32_bf16(a0, b1, acc[0][1], 0, 0, 0);
            acc[0][2] = __builtin_amdgcn_mfma_f32_16x16x32_bf16(a0, b2, acc[0][2], 0, 0, 0);
            acc[0][3] = __builtin_amdgcn_mfma_f32_16x16x32_bf16(a0, b3, acc[0][3], 0, 0, 0);
            acc[1][0] = __builtin_amdgcn_mfma_f32_16x16x32_bf16(a1, b0, acc[1][0], 0, 0, 0);
            acc[1][1] = __builtin_amdgcn_mfma_f32_16x16x32_bf16(a1, b1, acc[1][1], 0, 0, 0);
            acc[1][2] = __builtin_amdgcn_mfma_f32_16x16x32_bf16(a1, b2, acc[1][2], 0, 0, 0);
            acc[1][3] = __builtin_amdgcn_mfma_f32_16x16x32_bf16(a1, b3, acc[1][3], 0, 0, 0);
        }
    }

    // write partials: C/D layout col = lane&15, row = (lane>>4)*4 + e
    #pragma unroll
    for (int mt_ = 0; mt_ < 2; ++mt_)
        #pragma unroll
        for (int nt_ = 0; nt_ < 4; ++nt_) {
            const int col = wn * 64 + nt_ * 16 + (lane & 15);
            const int rw  = row0 + wm * 32 + mt_ * 16 + ((lane >> 4) << 2);
            float* dst = part + ((size_t)ks * N_PTS + rw) * 128 + col;
            #pragma unroll
            for (int e = 0; e < 4; ++e)
                dst[(size_t)e * 128] = acc[mt_][nt_][e];
        }
}

// ---------------------------------------------------------------------------
// Kernel 3: reduce split-K partials, apply W_proj / dir / t / bias
// ---------------------------------------------------------------------------
__global__ void epilogue(const float* __restrict__ part, const float* __restrict__ dir,
                         const float* __restrict__ t, const float* __restrict__ Wproj,
                         const float* __restrict__ bproj, float* __restrict__ out) {
    const int n = blockIdx.x;
    const int c = threadIdx.x;   // 0..127
    float s = 0.f;
    #pragma unroll
    for (int ks = 0; ks < KSPLIT; ++ks)
        s += part[((size_t)ks * N_PTS + n) * 128 + c];
    __shared__ float sm[128];
    sm[c] = s;
    __syncthreads();
    if (c < 4) {
        float a = bproj[c];
        for (int j = 0; j < 128; ++j)
            a += sm[j] * Wproj[c * 132 + j];
        a += dir[3 * n]     * Wproj[c * 132 + 128];
        a += dir[3 * n + 1] * Wproj[c * 132 + 129];
        a += dir[3 * n + 2] * Wproj[c * 132 + 130];
        a += t[n]           * Wproj[c * 132 + 131];
        out[n * 4 + c] = a;
    }
}

// ---------------------------------------------------------------------------
extern "C" void kernel_launch(void* const* d_in, const int* in_sizes, int n_in,
                              void* d_out, int out_size, void* d_ws, size_t ws_size,
                              hipStream_t stream) {
    const float* pos    = (const float*)d_in[0];
    const float* dir    = (const float*)d_in[1];
    const float* t      = (const float*)d_in[2];
    const float* table0 = (const float*)d_in[3];
    const float* table1 = (const float*)d_in[4];
    const float* table2 = (const float*)d_in[5];
    const float* table3 = (const float*)d_in[6];
    const float* ts1    = (const float*)d_in[7];
    const float* ts2    = (const float*)d_in[8];
    const float* Wm     = (const float*)d_in[9];
    const float* Wproj  = (const float*)d_in[10];
    const float* bproj  = (const float*)d_in[11];
    float* out = (float*)d_out;

    char* ws = (char*)d_ws;
    unsigned short* Wp = (unsigned short*)(ws);                         //  9,699,328 B
    float* dense = (float*)(ws + 9699328);                              //  8,388,608 B
    int*   bases = (int*)(ws + 9699328 + 8388608);                      //     16,384 B
    float* part  = (float*)(ws + 9699328 + 8388608 + 16384);            // 33,554,432 B
    // total ws usage: 51,658,752 B

    hipLaunchKernelGGL(setup_kernel, dim3(PACK_BLOCKS + N_PTS), dim3(256), 0, stream,
                       Wm, Wp, pos, t, table0, table1, ts1, ts2, dense, bases);
    hipLaunchKernelGGL(gemm_kernel, dim3(KSPLIT, 32), dim3(256), 0, stream,
                       dense, table2, table3, bases, Wp, part);
    hipLaunchKernelGGL(epilogue, dim3(N_PTS), dim3(128), 0, stream,
                       part, dir, t, Wproj, bproj, out);
}

// Round 3
// 86.513 us; speedup vs baseline: 1.2336x; 1.2336x over previous
//
#include <hip/hip_runtime.h>

// ---------------------------------------------------------------------------
// SpaceTimeStepLookTable: fused gather + relu + bf16 MFMA GEMM + projection
//
// Feature layout (original k): f0[0,64) f1[64,576) f2[576,4672) f3[4672,37440)
//                              time[37440,37632) nb[37632,37848)
// Packed layout (kp):  dense[0,1024) = [f0|f1|time|nb|zeros40]
//                      f2   [1024,5120)
//                      f3   [5120,37888)
//
// Round-3: round-1 structure (KSPLIT=16) + double-buffered LDS GEMM with one
// barrier per chunk, loads issued before MFMA / consumed after (T14 split),
// 512-thread blocks (8 waves, 32x32 wave tiles) for 4 waves/SIMD TLP.
// ---------------------------------------------------------------------------

typedef short s16x8 __attribute__((ext_vector_type(8)));
typedef float f32x4 __attribute__((ext_vector_type(4)));

#define N_PTS 2048
#define KP_TOTAL 37888
#define K_ORIG 37848
#define BM 64
#define BK 64
#define KSPLIT 16
#define CHUNKS_PER_KS 37          // 592 / 16
#define LDS_PAD 72                // bf16 elems per LDS row (144B: balanced banks)

__device__ __forceinline__ unsigned short f2bf(float x) {
    unsigned u = __builtin_bit_cast(unsigned, x);
    u = (u + 0x7FFFu + ((u >> 16) & 1u)) >> 16;   // RNE
    return (unsigned short)u;
}

// ---------------------------------------------------------------------------
// Kernel 1: pack W_mlp (fp32, original k layout) -> bf16, permuted kp layout
// grid (148, 128) x 256 : 148*256 == 37888 exactly
// ---------------------------------------------------------------------------
__global__ void pack_w(const float* __restrict__ Wm, unsigned short* __restrict__ Wp) {
    const int kp = blockIdx.x * 256 + threadIdx.x;   // [0,37888)
    const int c  = blockIdx.y;                       // [0,128)
    int k; bool valid = true;
    if (kp < 576)        k = kp;                       // f0+f1
    else if (kp < 768)   k = 37440 + (kp - 576);       // time
    else if (kp < 984)   k = 37632 + (kp - 768);       // nb
    else if (kp < 1024)  { k = 0; valid = false; }     // zero pad
    else if (kp < 5120)  k = 576 + (kp - 1024);        // f2
    else                 k = 4672 + (kp - 5120);       // f3
    const float w = valid ? Wm[(size_t)c * K_ORIG + k] : 0.f;
    Wp[(size_t)c * KP_TOTAL + kp] = f2bf(w);
}

// ---------------------------------------------------------------------------
// Kernel 2: per-point prep — materialize dense segment (f0|f1|time|nb|pad)
// grid 2048 x 256
// ---------------------------------------------------------------------------
__global__ void prep(const float* __restrict__ pos, const float* __restrict__ t,
                     const float* __restrict__ table0, const float* __restrict__ table1,
                     const float* __restrict__ ts1, const float* __restrict__ ts2,
                     float* __restrict__ dense, int* __restrict__ bases) {
    const int n = blockIdx.x;
    const int tid = threadIdx.x;
    const float px = pos[3 * n], py = pos[3 * n + 1], pz = pos[3 * n + 2];
    const float tv = t[n];
    const int i0 = (int)(px * 127.f), j0 = (int)(py * 127.f), k0 = (int)(pz * 127.f);
    const int i1 = (int)(px * 63.f),  j1 = (int)(py * 63.f),  k1 = (int)(pz * 63.f);
    const int i2 = (int)(px * 31.f),  j2 = (int)(py * 31.f),  k2 = (int)(pz * 31.f);
    const int i3 = (int)(px * 15.f),  j3 = (int)(py * 15.f),  k3 = (int)(pz * 15.f);
    const int ti = (int)(tv * 127.f);

    float* drow = dense + (size_t)n * 1024;

    if (tid < 64)
        drow[tid] = table0[(size_t)(((i0 * 128 + j0) * 128 + k0)) * 64 + tid];
    #pragma unroll
    for (int e = tid; e < 512; e += 256)
        drow[64 + e] = table1[(size_t)(((i1 * 64 + j1) * 64 + k1)) * 512 + e];
    if (tid < 192) {
        const int d = tid >> 6, e = tid & 63;
        const int tw = (ti + d - 1 + 64) & 63;
        drow[576 + tid] = ts1[((size_t)(((i3 * 16 + j3) * 16 + k3)) * 64 + tw) * 64 + e];
    }
    if (tid < 216) {
        const int o = tid >> 2, cc = tid & 3;
        const int dt_ = (o & 1) ? 1 : -1;
        const int rest = o >> 1;
        const int dz_ = rest % 3 - 1;
        const int dy_ = (rest / 3) % 3 - 1;
        const int dx_ = rest / 9 - 1;
        const int x = (i3 + dx_ + 128) & 127;
        const int y = (j3 + dy_ + 128) & 127;
        const int z = (k3 + dz_ + 128) & 127;
        const int w = (ti + dt_ + 128) & 127;
        drow[768 + tid] = ts2[(((((size_t)x * 128 + y) * 128 + z) * 128 + w) * 4) + cc];
    } else if (tid >= 216 && tid < 256) {
        drow[768 + tid] = 0.f;    // kp [984,1024) zero pad
    }
    if (tid == 0) {
        bases[2 * n]     = ((i2 * 32 + j2) * 32 + k2) * 4096;   // f2 row base (elements)
        bases[2 * n + 1] = ((i3 * 16 + j3) * 16 + k3) * 32768;  // f3 row base (elements)
    }
}

// ---------------------------------------------------------------------------
// Kernel 3: fused gather->relu->bf16 GEMM. C = relu(A) * W^T, split-K.
// grid (16, 32) x 512 threads (8 waves, each a 32x32 tile of the 64x128 block).
// Double-buffered LDS, ONE barrier per chunk:
//   issue loads(c+1) -> MFMA on buf[cur] -> convert+write buf[cur^1] -> barrier
// ---------------------------------------------------------------------------
__global__ __launch_bounds__(512, 4) void gemm_kernel(
    const float* __restrict__ dense, const float* __restrict__ table2,
    const float* __restrict__ table3, const int* __restrict__ bases,
    const unsigned short* __restrict__ Wp, float* __restrict__ part) {

    __shared__ unsigned short Alds[2][BM][LDS_PAD];
    __shared__ unsigned short Wlds[2][128][LDS_PAD];

    const int ks = blockIdx.x;
    const int mt = blockIdx.y;
    const int row0 = mt * BM;
    const int tid = threadIdx.x;
    const int lane = tid & 63;
    const int wave = tid >> 6;     // 0..7
    const int wm = wave >> 2;      // 0..1 (32-row half)
    const int wn = wave & 3;       // 0..3 (32-col quarter)

    // A staging: each thread loads 8 consecutive fp32 of one row (2x float4)
    const int arow = tid >> 3;            // 0..63
    const int acol = (tid & 7) * 8;       // 0..56
    const int an = row0 + arow;
    const int f2b = bases[2 * an];
    const int f3b = bases[2 * an + 1];
    const float* drow = dense + (size_t)an * 1024;

    // W staging: each thread copies 16 bf16 of one row (2x s16x8)
    const int wrow = tid >> 2;            // 0..127
    const int wcol = (tid & 3) * 16;      // 0,16,32,48
    const unsigned short* wrowp = Wp + (size_t)wrow * KP_TOTAL;

    f32x4 acc[2][2];
    #pragma unroll
    for (int i = 0; i < 2; ++i)
        #pragma unroll
        for (int j = 0; j < 2; ++j)
            acc[i][j] = (f32x4){0.f, 0.f, 0.f, 0.f};

    const int cbeg = ks * CHUNKS_PER_KS;
    const int cend = cbeg + CHUNKS_PER_KS;

    float4 av0, av1;
    s16x8 wv0, wv1;

    auto load_regs = [&](int c) {
        const int kp0 = c * BK;
        const float* asrc;
        if (kp0 < 1024)      asrc = drow + kp0 + acol;
        else if (kp0 < 5120) asrc = table2 + (size_t)f2b + (kp0 - 1024) + acol;
        else                 asrc = table3 + (size_t)f3b + (kp0 - 5120) + acol;
        av0 = ((const float4*)asrc)[0];
        av1 = ((const float4*)asrc)[1];
        const s16x8* wsrc = (const s16x8*)(wrowp + kp0 + wcol);
        wv0 = wsrc[0]; wv1 = wsrc[1];
    };

    auto convert_write = [&](int buf) {
        float va[8];
        *(float4*)&va[0] = av0; *(float4*)&va[4] = av1;
        s16x8 o;
        #pragma unroll
        for (int e = 0; e < 8; ++e)
            o[e] = (short)f2bf(fmaxf(va[e], 0.f));
        *(s16x8*)&Alds[buf][arow][acol]     = o;
        *(s16x8*)&Wlds[buf][wrow][wcol]     = wv0;
        *(s16x8*)&Wlds[buf][wrow][wcol + 8] = wv1;
    };

    // prologue: stage first chunk into buf 0
    load_regs(cbeg);
    convert_write(0);
    __syncthreads();

    const int r  = lane & 15;
    const int hi = lane >> 4;
    int cur = 0;

    for (int c = cbeg; c < cend; ++c) {
        const bool has_next = (c + 1) < cend;
        if (has_next) load_regs(c + 1);   // issue early: latency hides under MFMAs

        #pragma unroll
        for (int kk = 0; kk < 2; ++kk) {
            const int ko = kk * 32 + hi * 8;
            const s16x8 a0 = *(const s16x8*)&Alds[cur][wm * 32 + r][ko];
            const s16x8 a1 = *(const s16x8*)&Alds[cur][wm * 32 + 16 + r][ko];
            const s16x8 b0 = *(const s16x8*)&Wlds[cur][wn * 32 + r][ko];
            const s16x8 b1 = *(const s16x8*)&Wlds[cur][wn * 32 + 16 + r][ko];
            acc[0][0] = __builtin_amdgcn_mfma_f32_16x16x32_bf16(a0, b0, acc[0][0], 0, 0, 0);
            acc[0][1] = __builtin_amdgcn_mfma_f32_16x16x32_bf16(a0, b1, acc[0][1], 0, 0, 0);
            acc[1][0] = __builtin_amdgcn_mfma_f32_16x16x32_bf16(a1, b0, acc[1][0], 0, 0, 0);
            acc[1][1] = __builtin_amdgcn_mfma_f32_16x16x32_bf16(a1, b1, acc[1][1], 0, 0, 0);
        }

        if (has_next) convert_write(cur ^ 1);   // vmcnt wait lands here, after MFMAs
        __syncthreads();
        cur ^= 1;
    }

    // write partials: C/D layout col = lane&15, row = (lane>>4)*4 + e
    #pragma unroll
    for (int mt_ = 0; mt_ < 2; ++mt_)
        #pragma unroll
        for (int nt_ = 0; nt_ < 2; ++nt_) {
            const int col = wn * 32 + nt_ * 16 + (lane & 15);
            const int rw  = row0 + wm * 32 + mt_ * 16 + ((lane >> 4) << 2);
            float* dst = part + ((size_t)ks * N_PTS + rw) * 128 + col;
            #pragma unroll
            for (int e = 0; e < 4; ++e)
                dst[(size_t)e * 128] = acc[mt_][nt_][e];
        }
}

// ---------------------------------------------------------------------------
// Kernel 4: reduce split-K partials, apply W_proj / dir / t / bias
// ---------------------------------------------------------------------------
__global__ void epilogue(const float* __restrict__ part, const float* __restrict__ dir,
                         const float* __restrict__ t, const float* __restrict__ Wproj,
                         const float* __restrict__ bproj, float* __restrict__ out) {
    const int n = blockIdx.x;
    const int c = threadIdx.x;   // 0..127
    float s = 0.f;
    #pragma unroll
    for (int ks = 0; ks < KSPLIT; ++ks)
        s += part[((size_t)ks * N_PTS + n) * 128 + c];
    __shared__ float sm[128];
    sm[c] = s;
    __syncthreads();
    if (c < 4) {
        float a = bproj[c];
        for (int j = 0; j < 128; ++j)
            a += sm[j] * Wproj[c * 132 + j];
        a += dir[3 * n]     * Wproj[c * 132 + 128];
        a += dir[3 * n + 1] * Wproj[c * 132 + 129];
        a += dir[3 * n + 2] * Wproj[c * 132 + 130];
        a += t[n]           * Wproj[c * 132 + 131];
        out[n * 4 + c] = a;
    }
}

// ---------------------------------------------------------------------------
extern "C" void kernel_launch(void* const* d_in, const int* in_sizes, int n_in,
                              void* d_out, int out_size, void* d_ws, size_t ws_size,
                              hipStream_t stream) {
    const float* pos    = (const float*)d_in[0];
    const float* dir    = (const float*)d_in[1];
    const float* t      = (const float*)d_in[2];
    const float* table0 = (const float*)d_in[3];
    const float* table1 = (const float*)d_in[4];
    const float* table2 = (const float*)d_in[5];
    const float* table3 = (const float*)d_in[6];
    const float* ts1    = (const float*)d_in[7];
    const float* ts2    = (const float*)d_in[8];
    const float* Wm     = (const float*)d_in[9];
    const float* Wproj  = (const float*)d_in[10];
    const float* bproj  = (const float*)d_in[11];
    float* out = (float*)d_out;

    char* ws = (char*)d_ws;
    unsigned short* Wp = (unsigned short*)(ws);                         //  9,699,328 B
    float* dense = (float*)(ws + 9699328);                              //  8,388,608 B
    int*   bases = (int*)(ws + 9699328 + 8388608);                      //     16,384 B
    float* part  = (float*)(ws + 9699328 + 8388608 + 16384);            // 16,777,216 B
    // total ws usage: 34,881,536 B

    hipLaunchKernelGGL(pack_w, dim3(148, 128), dim3(256), 0, stream, Wm, Wp);
    hipLaunchKernelGGL(prep, dim3(N_PTS), dim3(256), 0, stream,
                       pos, t, table0, table1, ts1, ts2, dense, bases);
    hipLaunchKernelGGL(gemm_kernel, dim3(KSPLIT, 32), dim3(512), 0, stream,
                       dense, table2, table3, bases, Wp, part);
    hipLaunchKernelGGL(epilogue, dim3(N_PTS), dim3(128), 0, stream,
                       part, dir, t, Wproj, bproj, out);
}